// Round 1
// baseline (642.347 us; speedup 1.0000x reference)
//
#include <hip/hip_runtime.h>
#include <hip/hip_bf16.h>

using bf16 = __hip_bfloat16;
typedef __attribute__((ext_vector_type(8))) short short8v;
typedef __attribute__((ext_vector_type(4))) float f32x4;

#define MFMA16(a,b,c) __builtin_amdgcn_mfma_f32_16x16x32_bf16((a),(b),(c),0,0,0)

static constexpr int Bn = 8;
static constexpr int Ll = 56 * 56;      // 3136
static constexpr int Mrows = Bn * Ll;   // 25088

__device__ __forceinline__ void gload16(const void* g, void* l) {
  __builtin_amdgcn_global_load_lds(
      (const __attribute__((address_space(1))) void*)g,
      (__attribute__((address_space(3))) void*)l, 16, 0, 0);
}

// ---------------- LayerNorm: x f32 (row=256) -> bf16 ----------------
__global__ __launch_bounds__(256) void ln_kernel(const float* __restrict__ x,
    const float* __restrict__ g, const float* __restrict__ b,
    bf16* __restrict__ out) {
  int lane = threadIdx.x & 63;
  int row = blockIdx.x * 4 + (threadIdx.x >> 6);
  const float4 v = *reinterpret_cast<const float4*>(x + (size_t)row * 256 + lane * 4);
  float s = v.x + v.y + v.z + v.w;
  float sq = v.x * v.x + v.y * v.y + v.z * v.z + v.w * v.w;
#pragma unroll
  for (int m = 1; m < 64; m <<= 1) {
    s += __shfl_xor(s, m, 64);
    sq += __shfl_xor(sq, m, 64);
  }
  float mean = s * (1.0f / 256.0f);
  float rstd = rsqrtf(sq * (1.0f / 256.0f) - mean * mean + 1e-5f);
  const float4 gg = *reinterpret_cast<const float4*>(g + lane * 4);
  const float4 bb = *reinterpret_cast<const float4*>(b + lane * 4);
  bf16 o[4];
  o[0] = __float2bfloat16((v.x - mean) * rstd * gg.x + bb.x);
  o[1] = __float2bfloat16((v.y - mean) * rstd * gg.y + bb.y);
  o[2] = __float2bfloat16((v.z - mean) * rstd * gg.z + bb.z);
  o[3] = __float2bfloat16((v.w - mean) * rstd * gg.w + bb.w);
  *reinterpret_cast<uint2*>(out + (size_t)row * 256 + lane * 4) =
      *reinterpret_cast<const uint2*>(o);
}

// -------- weight transpose: in (K,N) f32 row-major -> out (N,K) bf16 --------
__global__ void wtrans_kernel(const float* __restrict__ in, bf16* __restrict__ out,
                              int K, int N) {
  int total = K * N;
  for (int idx = blockIdx.x * 256 + threadIdx.x; idx < total; idx += gridDim.x * 256) {
    int n = idx / K, k = idx - n * K;
    out[idx] = __float2bfloat16(in[(size_t)k * N + n]);
  }
}

// ---------------- GEMM: C = A(MxK) * Bt(NxK)^T, epilogues ----------------
// EPI 0: bf16 out = acc + bias
// EPI 1: bf16 out = gelu(acc + bias)   (exact erf gelu)
// EPI 2: f32  out += acc + bias        (residual accumulate)
template <int EPI>
__global__ __launch_bounds__(256) void gemm_kernel(
    const bf16* __restrict__ A, const bf16* __restrict__ Bt,
    const float* __restrict__ bias, void* __restrict__ outp,
    int M, int N, int K) {
  __shared__ bf16 Al[128 * 64];
  __shared__ bf16 Bl[128 * 64];
  int tid = threadIdx.x, lane = tid & 63, wid = tid >> 6;
  int brow = blockIdx.y, bcol = blockIdx.x;
  int wrow = wid >> 1, wcol = wid & 1;
  f32x4 acc[4][4];
#pragma unroll
  for (int i = 0; i < 4; i++)
#pragma unroll
    for (int j = 0; j < 4; j++) acc[i][j] = f32x4{0.f, 0.f, 0.f, 0.f};

  int r8 = lane >> 3;
  int c8 = (lane & 7) * 8;
  const bf16* ga0 = A + (size_t)(brow * 128 + r8) * K + c8;
  const bf16* gb0 = Bt + (size_t)(bcol * 128 + r8) * K + c8;

  for (int kt = 0; kt < K; kt += 64) {
    __syncthreads();  // previous iteration's LDS reads done
#pragma unroll
    for (int c = 0; c < 4; c++) {
      int chunk = c * 4 + wid;  // wave-uniform
      gload16(ga0 + (size_t)chunk * 8 * K + kt, Al + chunk * 512);
      gload16(gb0 + (size_t)chunk * 8 * K + kt, Bl + chunk * 512);
    }
    __syncthreads();  // drains vmcnt (global_load_lds) per compiler semantics
#pragma unroll
    for (int kk = 0; kk < 64; kk += 32) {
      short8v av[4], bv[4];
#pragma unroll
      for (int mi = 0; mi < 4; mi++)
        av[mi] = *reinterpret_cast<const short8v*>(
            &Al[(wrow * 64 + mi * 16 + (lane & 15)) * 64 + kk + (lane >> 4) * 8]);
#pragma unroll
      for (int ni = 0; ni < 4; ni++)
        bv[ni] = *reinterpret_cast<const short8v*>(
            &Bl[(wcol * 64 + ni * 16 + (lane & 15)) * 64 + kk + (lane >> 4) * 8]);
#pragma unroll
      for (int mi = 0; mi < 4; mi++)
#pragma unroll
        for (int ni = 0; ni < 4; ni++)
          acc[mi][ni] = MFMA16(av[mi], bv[ni], acc[mi][ni]);
    }
  }

  int rowb = brow * 128 + wrow * 64 + ((lane >> 4) * 4);
  int colb = bcol * 128 + wcol * 64 + (lane & 15);
#pragma unroll
  for (int ni = 0; ni < 4; ni++) {
    int col = colb + ni * 16;
    float bvl = bias[col];
#pragma unroll
    for (int mi = 0; mi < 4; mi++) {
#pragma unroll
      for (int r = 0; r < 4; r++) {
        int row = rowb + mi * 16 + r;
        float v = acc[mi][ni][r] + bvl;
        if (EPI == 0) {
          ((bf16*)outp)[(size_t)row * N + col] = __float2bfloat16(v);
        } else if (EPI == 1) {
          float gv = 0.5f * v * (1.0f + erff(v * 0.70710678118654752f));
          ((bf16*)outp)[(size_t)row * N + col] = __float2bfloat16(gv);
        } else {
          float* o = (float*)outp + (size_t)row * N + col;
          *o += v;
        }
      }
    }
  }
}

// ---------------- Attention: one block per (branch, window, head) ----------------
// qkv: (B, L, 768) bf16; att out: (B, L, 256) bf16 (written, lepe adds later)
__global__ __launch_bounds__(256) void attn_kernel(const bf16* __restrict__ qkv,
                                                   bf16* __restrict__ att) {
  __shared__ bf16 Kl[416 * 40];     // [token][d], stride 40
  __shared__ bf16 Vt[32 * 424];     // [d][token], stride 424
  __shared__ bf16 Pl[4][16 * 40];   // per-wave P transpose scratch

  int tid = threadIdx.x, lane = tid & 63, wid = tid >> 6;
  int wh = blockIdx.x;              // 0..511
  int branch = wh >> 8;
  int head = wh & 3;
  int widx = (wh >> 2) & 63;
  int bimg = widx >> 3, g = widx & 7;
  int cb = branch * 128 + head * 32;
  size_t base = (size_t)bimg * Ll * 768;

  // token (0..391) -> flat l index. branch0: 56x7 window, branch1: 7x56 window.
  auto tok2l = [&](int t) -> int {
    if (branch == 0) { int d = t / 7;  return d * 56 + g * 7 + (t - d * 7); }
    else             { int d = t / 56; return (g * 7 + d) * 56 + (t - d * 56); }
  };

  // stage K and V^T
  for (int idx = tid; idx < 392 * 4; idx += 256) {
    int t = idx >> 2, dq = (idx & 3) * 8;
    size_t go = base + (size_t)tok2l(t) * 768 + cb + dq;
    uint4 kv = *reinterpret_cast<const uint4*>(qkv + go + 256);
    *reinterpret_cast<uint4*>(&Kl[t * 40 + dq]) = kv;
    uint4 vv = *reinterpret_cast<const uint4*>(qkv + go + 512);
    const bf16* pv = reinterpret_cast<const bf16*>(&vv);
#pragma unroll
    for (int j = 0; j < 8; j++) Vt[(dq + j) * 424 + t] = pv[j];
  }
  bf16 z16 = __float2bfloat16(0.0f);
  for (int idx = tid; idx < 768; idx += 256) {  // zero the 392..415 pad
    Kl[(392 + (idx >> 5)) * 40 + (idx & 31)] = z16;
    Vt[(idx & 31) * 424 + 392 + (idx >> 5)] = z16;
  }
  __syncthreads();

  const float scale = 0.17677669529663687f;  // 1/sqrt(32)
  for (int mt = wid; mt < 25; mt += 4) {      // 25 M-tiles of 16 q (padded 400)
    int qr = mt * 16 + (lane & 15);
    if (qr > 391) qr = 391;
    short8v qf = *reinterpret_cast<const short8v*>(
        qkv + base + (size_t)tok2l(qr) * 768 + cb + (lane >> 4) * 8);
    f32x4 o0 = {0.f, 0.f, 0.f, 0.f}, o1 = {0.f, 0.f, 0.f, 0.f};
    float mrun[4] = {-1e30f, -1e30f, -1e30f, -1e30f};
    float lrun[4] = {0.f, 0.f, 0.f, 0.f};

    for (int kt = 0; kt < 13; kt++) {
      int kb = kt * 32;
      short8v kf0 = *reinterpret_cast<const short8v*>(
          &Kl[(kb + (lane & 15)) * 40 + (lane >> 4) * 8]);
      short8v kf1 = *reinterpret_cast<const short8v*>(
          &Kl[(kb + 16 + (lane & 15)) * 40 + (lane >> 4) * 8]);
      f32x4 zz = {0.f, 0.f, 0.f, 0.f};
      f32x4 s0 = MFMA16(qf, kf0, zz);
      f32x4 s1 = MFMA16(qf, kf1, zz);
      bool v0 = (kb + (lane & 15)) < 392;
      bool v1 = (kb + 16 + (lane & 15)) < 392;
      float p0[4], p1[4];
#pragma unroll
      for (int r = 0; r < 4; r++) {
        float a = v0 ? s0[r] * scale : -1e30f;
        float c = v1 ? s1[r] * scale : -1e30f;
        float t = fmaxf(a, c);
        t = fmaxf(t, __shfl_xor(t, 1, 64));
        t = fmaxf(t, __shfl_xor(t, 2, 64));
        t = fmaxf(t, __shfl_xor(t, 4, 64));
        t = fmaxf(t, __shfl_xor(t, 8, 64));
        float mn = fmaxf(mrun[r], t);
        float al = __expf(mrun[r] - mn);
        mrun[r] = mn;
        p0[r] = __expf(a - mn);
        p1[r] = __expf(c - mn);
        float rs = p0[r] + p1[r];
        rs += __shfl_xor(rs, 1, 64);
        rs += __shfl_xor(rs, 2, 64);
        rs += __shfl_xor(rs, 4, 64);
        rs += __shfl_xor(rs, 8, 64);
        lrun[r] = lrun[r] * al + rs;
        o0[r] *= al;
        o1[r] *= al;
      }
      // transpose P through per-wave LDS into A-fragment layout
      bf16* pw = &Pl[wid][0];
#pragma unroll
      for (int r = 0; r < 4; r++) {
        int prow = (lane >> 4) * 4 + r;
        pw[prow * 40 + (lane & 15)] = __float2bfloat16(p0[r]);
        pw[prow * 40 + 16 + (lane & 15)] = __float2bfloat16(p1[r]);
      }
      short8v pf = *reinterpret_cast<const short8v*>(&pw[(lane & 15) * 40 + (lane >> 4) * 8]);
      short8v vf0 = *reinterpret_cast<const short8v*>(
          &Vt[(lane & 15) * 424 + kb + (lane >> 4) * 8]);
      short8v vf1 = *reinterpret_cast<const short8v*>(
          &Vt[(16 + (lane & 15)) * 424 + kb + (lane >> 4) * 8]);
      o0 = MFMA16(pf, vf0, o0);
      o1 = MFMA16(pf, vf1, o1);
    }

#pragma unroll
    for (int r = 0; r < 4; r++) {
      int q = mt * 16 + (lane >> 4) * 4 + r;
      if (q < 392) {
        float inv = 1.0f / lrun[r];
        size_t ob = ((size_t)bimg * Ll + tok2l(q)) * 256 + cb + (lane & 15);
        att[ob] = __float2bfloat16(o0[r] * inv);
        att[ob + 16] = __float2bfloat16(o1[r] * inv);
      }
    }
  }
}

// ---------------- LePE depthwise 3x3 (window-local SAME), adds into att ----------------
__global__ __launch_bounds__(256) void lepe_kernel(const bf16* __restrict__ qkv,
    const float* __restrict__ w0, const float* __restrict__ b0,
    const float* __restrict__ w1, const float* __restrict__ b1,
    bf16* __restrict__ att) {
  int idx = blockIdx.x * 256 + threadIdx.x;  // B*L*256 total
  int ch = idx & 255;
  int pos = idx >> 8;  // b*L + l
  int l = pos % Ll;
  int h = l / 56, w = l - (l / 56) * 56;
  int branch = ch >> 7, c2 = ch & 127;
  const float* wp = (branch ? w1 : w0) + c2 * 9;
  float bias = (branch ? b1 : b0)[c2];
  const bf16* vp = qkv + (size_t)pos * 768 + 512 + branch * 128 + c2;
  int lh = branch ? (h % 7) : h;
  int hmax = branch ? 7 : 56;
  int lw = branch ? w : (w % 7);
  int wmax = branch ? 56 : 7;
  float s = bias;
#pragma unroll
  for (int dy = -1; dy <= 1; dy++) {
#pragma unroll
    for (int dx = -1; dx <= 1; dx++) {
      bool ok = (unsigned)(lh + dy) < (unsigned)hmax && (unsigned)(lw + dx) < (unsigned)wmax;
      if (ok)
        s += wp[(dy + 1) * 3 + (dx + 1)] *
             __bfloat162float(vp[(dy * 56 + dx) * 768]);
    }
  }
  size_t o = (size_t)pos * 256 + ch;
  att[o] = __float2bfloat16(__bfloat162float(att[o]) + s);
}

// ---------------- host ----------------
extern "C" void kernel_launch(void* const* d_in, const int* in_sizes, int n_in,
                              void* d_out, int out_size, void* d_ws, size_t ws_size,
                              hipStream_t stream) {
  const float* x_in    = (const float*)d_in[0];
  const float* ln1_g   = (const float*)d_in[1];
  const float* ln1_b   = (const float*)d_in[2];
  const float* qkv_w   = (const float*)d_in[3];
  const float* qkv_b   = (const float*)d_in[4];
  const float* lepe_w0 = (const float*)d_in[5];
  const float* lepe_b0 = (const float*)d_in[6];
  const float* lepe_w1 = (const float*)d_in[7];
  const float* lepe_b1 = (const float*)d_in[8];
  const float* proj_w  = (const float*)d_in[9];
  const float* proj_b  = (const float*)d_in[10];
  const float* ln2_g   = (const float*)d_in[11];
  const float* ln2_b   = (const float*)d_in[12];
  const float* fc1_w   = (const float*)d_in[13];
  const float* fc1_b   = (const float*)d_in[14];
  const float* fc2_w   = (const float*)d_in[15];
  const float* fc2_b   = (const float*)d_in[16];
  float* xf = (float*)d_out;

  char* ws = (char*)d_ws;
  bf16* wT   = (bf16*)ws;                                   // 3,145,728 B
  bf16* bufA = (bf16*)(ws + 3145728);                       // qkv / mlp-h: 51,380,224 B
  bf16* imgB = (bf16*)(ws + 3145728 + 51380224);            // 12,845,056 B
  bf16* attB = (bf16*)(ws + 3145728 + 51380224 + 12845056); // 12,845,056 B

  // x <- input (residual stream lives in d_out, f32)
  hipMemcpyAsync(d_out, (const void*)x_in, (size_t)Mrows * 256 * 4,
                 hipMemcpyDeviceToDevice, stream);

  // transpose+cast all weights to bf16 [N][K]
  for (int l = 0; l < 2; l++) {
    bf16* qkvT = wT + (size_t)l * 786432;
    bf16* projT = qkvT + 196608;
    bf16* fc1T  = qkvT + 262144;
    bf16* fc2T  = qkvT + 524288;
    wtrans_kernel<<<256, 256, 0, stream>>>(qkv_w + l * 196608, qkvT, 256, 768);
    wtrans_kernel<<<128, 256, 0, stream>>>(proj_w + l * 65536, projT, 256, 256);
    wtrans_kernel<<<256, 256, 0, stream>>>(fc1_w + l * 262144, fc1T, 256, 1024);
    wtrans_kernel<<<256, 256, 0, stream>>>(fc2_w + l * 262144, fc2T, 1024, 256);
  }

  for (int l = 0; l < 2; l++) {
    bf16* qkvT = wT + (size_t)l * 786432;
    bf16* projT = qkvT + 196608;
    bf16* fc1T  = qkvT + 262144;
    bf16* fc2T  = qkvT + 524288;

    ln_kernel<<<Mrows / 4, 256, 0, stream>>>(xf, ln1_g + l * 256, ln1_b + l * 256, imgB);
    gemm_kernel<0><<<dim3(6, 196), 256, 0, stream>>>(imgB, qkvT, qkv_b + l * 768,
                                                     bufA, Mrows, 768, 256);
    attn_kernel<<<512, 256, 0, stream>>>(bufA, attB);
    lepe_kernel<<<Mrows, 256, 0, stream>>>(bufA, lepe_w0 + l * 1152, lepe_b0 + l * 128,
                                           lepe_w1 + l * 1152, lepe_b1 + l * 128, attB);
    gemm_kernel<2><<<dim3(2, 196), 256, 0, stream>>>(attB, projT, proj_b + l * 256,
                                                     xf, Mrows, 256, 256);
    ln_kernel<<<Mrows / 4, 256, 0, stream>>>(xf, ln2_g + l * 256, ln2_b + l * 256, imgB);
    gemm_kernel<1><<<dim3(8, 196), 256, 0, stream>>>(imgB, fc1T, fc1_b + l * 1024,
                                                     bufA, Mrows, 1024, 256);
    gemm_kernel<2><<<dim3(2, 196), 256, 0, stream>>>(bufA, fc2T, fc2_b + l * 256,
                                                     xf, Mrows, 256, 1024);
  }
}

// Round 2
// 600.575 us; speedup vs baseline: 1.0696x; 1.0696x over previous
//
#include <hip/hip_runtime.h>
#include <hip/hip_bf16.h>

using bf16 = __hip_bfloat16;
typedef __attribute__((ext_vector_type(8))) short short8v;
typedef __attribute__((ext_vector_type(4))) float f32x4;

#define MFMA16(a,b,c) __builtin_amdgcn_mfma_f32_16x16x32_bf16((a),(b),(c),0,0,0)

static constexpr int Bn = 8;
static constexpr int Ll = 56 * 56;      // 3136
static constexpr int Mrows = Bn * Ll;   // 25088

__device__ __forceinline__ void gload16(const void* g, void* l) {
  __builtin_amdgcn_global_load_lds(
      (const __attribute__((address_space(1))) void*)g,
      (__attribute__((address_space(3))) void*)l, 16, 0, 0);
}

__device__ __forceinline__ unsigned pack2(float a, float b) {
  unsigned ua = (unsigned)__bfloat16_as_ushort(__float2bfloat16(a));
  unsigned ub = (unsigned)__bfloat16_as_ushort(__float2bfloat16(b));
  return ua | (ub << 16);
}

// ---------------- LayerNorm: x f32 (row=256) -> bf16 ----------------
__global__ __launch_bounds__(256) void ln_kernel(const float* __restrict__ x,
    const float* __restrict__ g, const float* __restrict__ b,
    bf16* __restrict__ out) {
  int lane = threadIdx.x & 63;
  int row = blockIdx.x * 4 + (threadIdx.x >> 6);
  const float4 v = *reinterpret_cast<const float4*>(x + (size_t)row * 256 + lane * 4);
  float s = v.x + v.y + v.z + v.w;
  float sq = v.x * v.x + v.y * v.y + v.z * v.z + v.w * v.w;
#pragma unroll
  for (int m = 1; m < 64; m <<= 1) {
    s += __shfl_xor(s, m, 64);
    sq += __shfl_xor(sq, m, 64);
  }
  float mean = s * (1.0f / 256.0f);
  float rstd = rsqrtf(sq * (1.0f / 256.0f) - mean * mean + 1e-5f);
  const float4 gg = *reinterpret_cast<const float4*>(g + lane * 4);
  const float4 bb = *reinterpret_cast<const float4*>(b + lane * 4);
  bf16 o[4];
  o[0] = __float2bfloat16((v.x - mean) * rstd * gg.x + bb.x);
  o[1] = __float2bfloat16((v.y - mean) * rstd * gg.y + bb.y);
  o[2] = __float2bfloat16((v.z - mean) * rstd * gg.z + bb.z);
  o[3] = __float2bfloat16((v.w - mean) * rstd * gg.w + bb.w);
  *reinterpret_cast<uint2*>(out + (size_t)row * 256 + lane * 4) =
      *reinterpret_cast<const uint2*>(o);
}

// -------- weight transpose: in (K,N) f32 row-major -> out (N,K) bf16 --------
__global__ void wtrans_kernel(const float* __restrict__ in, bf16* __restrict__ out,
                              int K, int N) {
  int total = K * N;
  for (int idx = blockIdx.x * 256 + threadIdx.x; idx < total; idx += gridDim.x * 256) {
    int n = idx / K, k = idx - n * K;
    out[idx] = __float2bfloat16(in[(size_t)k * N + n]);
  }
}

// ---------------- GEMM: C = A(MxK) * Bt(NxK)^T, 2-phase double-buffered ----------------
// EPI 0: bf16 out = acc + bias
// EPI 1: bf16 out = gelu(acc + bias)   (exact erf gelu)
// EPI 2: f32  out += acc + bias        (residual accumulate)
template <int EPI>
__global__ __launch_bounds__(256) void gemm_kernel(
    const bf16* __restrict__ A, const bf16* __restrict__ Bt,
    const float* __restrict__ bias, void* __restrict__ outp,
    int M, int N, int K) {
  __shared__ bf16 Al[2][128 * 64];
  __shared__ bf16 Bl[2][128 * 64];
  int tid = threadIdx.x, lane = tid & 63, wid = tid >> 6;
  int brow = blockIdx.y, bcol = blockIdx.x;
  int wrow = wid >> 1, wcol = wid & 1;
  f32x4 acc[4][4];
#pragma unroll
  for (int i = 0; i < 4; i++)
#pragma unroll
    for (int j = 0; j < 4; j++) acc[i][j] = f32x4{0.f, 0.f, 0.f, 0.f};

  int r8 = lane >> 3;
  int c8 = (lane & 7) * 8;
  const bf16* ga0 = A + (size_t)(brow * 128 + r8) * K + c8;
  const bf16* gb0 = Bt + (size_t)(bcol * 128 + r8) * K + c8;

  auto stage = [&](bf16* Ad, bf16* Bd, int kt) {
#pragma unroll
    for (int c = 0; c < 4; c++) {
      int chunk = c * 4 + wid;  // wave-uniform
      gload16(ga0 + (size_t)chunk * 8 * K + kt, Ad + chunk * 512);
      gload16(gb0 + (size_t)chunk * 8 * K + kt, Bd + chunk * 512);
    }
  };

  stage(Al[0], Bl[0], 0);
  asm volatile("s_waitcnt vmcnt(0)" ::: "memory");
  __builtin_amdgcn_s_barrier();

  int nk = K >> 6;
  int cur = 0;
  for (int t = 0; t < nk; t++) {
    bf16* Ac = Al[cur];
    bf16* Bc = Bl[cur];
    if (t + 1 < nk) stage(Al[cur ^ 1], Bl[cur ^ 1], (t + 1) * 64);
#pragma unroll
    for (int kk = 0; kk < 64; kk += 32) {
      short8v av[4], bv[4];
#pragma unroll
      for (int mi = 0; mi < 4; mi++)
        av[mi] = *reinterpret_cast<const short8v*>(
            &Ac[(wrow * 64 + mi * 16 + (lane & 15)) * 64 + kk + (lane >> 4) * 8]);
#pragma unroll
      for (int ni = 0; ni < 4; ni++)
        bv[ni] = *reinterpret_cast<const short8v*>(
            &Bc[(wcol * 64 + ni * 16 + (lane & 15)) * 64 + kk + (lane >> 4) * 8]);
#pragma unroll
      for (int mi = 0; mi < 4; mi++)
#pragma unroll
        for (int ni = 0; ni < 4; ni++)
          acc[mi][ni] = MFMA16(av[mi], bv[ni], acc[mi][ni]);
    }
    asm volatile("s_waitcnt vmcnt(0)" ::: "memory");
    __builtin_amdgcn_s_barrier();
    cur ^= 1;
  }

  int rowb = brow * 128 + wrow * 64 + ((lane >> 4) * 4);
  int colb = bcol * 128 + wcol * 64 + (lane & 15);
#pragma unroll
  for (int ni = 0; ni < 4; ni++) {
    int col = colb + ni * 16;
    float bvl = bias[col];
#pragma unroll
    for (int mi = 0; mi < 4; mi++) {
#pragma unroll
      for (int r = 0; r < 4; r++) {
        int row = rowb + mi * 16 + r;
        float v = acc[mi][ni][r] + bvl;
        if (EPI == 0) {
          ((bf16*)outp)[(size_t)row * N + col] = __float2bfloat16(v);
        } else if (EPI == 1) {
          float gv = 0.5f * v * (1.0f + erff(v * 0.70710678118654752f));
          ((bf16*)outp)[(size_t)row * N + col] = __float2bfloat16(gv);
        } else {
          float* o = (float*)outp + (size_t)row * N + col;
          *o += v;
        }
      }
    }
  }
}

// ---------------- Attention: one block per (branch, window, head) ----------------
// Swapped QK^T (S^T = K·Q^T) -> per-lane q-row scores -> register softmax ->
// shfl-exchange P into B-fragment -> o^T = V^T · P^T.
__global__ __launch_bounds__(256) void attn_kernel(const bf16* __restrict__ qkv,
                                                   bf16* __restrict__ att) {
  __shared__ bf16 Kl[400 * 40];   // [token][d], stride 40 (16B-aligned rows)
  __shared__ bf16 Vt[32 * 424];   // [d][token], stride 424 (16B-aligned rows)

  int tid = threadIdx.x, lane = tid & 63, wid = tid >> 6;
  int wh = blockIdx.x;              // 0..511
  int branch = wh >> 8;
  int head = wh & 3;
  int widx = (wh >> 2) & 63;
  int bimg = widx >> 3, g7 = widx & 7;
  int cb = branch * 128 + head * 32;
  size_t base = (size_t)bimg * Ll * 768;

  // token (0..391) -> flat l index. branch0: 56x7 window, branch1: 7x56 window.
  auto tok2l = [&](int t) -> int {
    if (branch == 0) { int d = t / 7;  return d * 56 + g7 * 7 + (t - d * 7); }
    else             { int d = t / 56; return (g7 * 7 + d) * 56 + (t - d * 56); }
  };

  // stage K [t][d] and V^T [d][t]
  for (int idx = tid; idx < 392 * 4; idx += 256) {
    int t = idx >> 2, dq = (idx & 3) * 8;
    size_t go = base + (size_t)tok2l(t) * 768 + cb + dq;
    uint4 kv = *reinterpret_cast<const uint4*>(qkv + go + 256);
    *reinterpret_cast<uint4*>(&Kl[t * 40 + dq]) = kv;
    uint4 vv = *reinterpret_cast<const uint4*>(qkv + go + 512);
    const bf16* pv = reinterpret_cast<const bf16*>(&vv);
#pragma unroll
    for (int j = 0; j < 8; j++) Vt[(dq + j) * 424 + t] = pv[j];
  }
  bf16 z16 = __float2bfloat16(0.0f);
  for (int idx = tid; idx < 320; idx += 256) Kl[392 * 40 + idx] = z16;  // rows 392..399
  for (int idx = tid; idx < 1024; idx += 256) {                          // cols 392..423
    int d = idx >> 5, c = idx & 31;
    Vt[d * 424 + 392 + c] = z16;
  }
  __syncthreads();

  const float c1 = 0.25506275154111575f;  // (1/sqrt(32)) * log2(e)
  const f32x4 zz = {0.f, 0.f, 0.f, 0.f};
  int lg = lane >> 4;                 // lane group 0..3
  int ql = lane & 15;                 // q column within tile
  int tsel = lg >> 1;
  int Lsrc = ((lg & 1) << 5) | ql;    // exchange source lane (group 2*(lg&1))

  for (int mt = wid; mt < 25; mt += 4) {   // 25 M-tiles of 16 q (padded 400)
    int qr = mt * 16 + ql;
    if (qr > 391) qr = 391;
    short8v qf = *reinterpret_cast<const short8v*>(
        qkv + base + (size_t)tok2l(qr) * 768 + cb + lg * 8);

    // ---- S^T tiles: s[t][r] = S[q=ql][k=16t+4*lg+r] ----
    f32x4 s[25];
#pragma unroll
    for (int t = 0; t < 25; t++) {
      short8v kf = *reinterpret_cast<const short8v*>(
          &Kl[(t * 16 + ql) * 40 + lg * 8]);
      s[t] = MFMA16(kf, qf, zz);
    }
    if (lg >= 2) s[24] = f32x4{-1e30f, -1e30f, -1e30f, -1e30f};  // k>=392 pad

    // ---- row max (4 lanes per q-row) ----
    float m = -1e30f;
#pragma unroll
    for (int t = 0; t < 25; t++)
      m = fmaxf(m, fmaxf(fmaxf(s[t][0], s[t][1]), fmaxf(s[t][2], s[t][3])));
    m = fmaxf(m, __shfl_xor(m, 16, 64));
    m = fmaxf(m, __shfl_xor(m, 32, 64));
    float mm = m * c1;

    // ---- exp + sum + pack to bf16 pairs ----
    float lsum = 0.f;
    unsigned pk[26][2];
#pragma unroll
    for (int t = 0; t < 25; t++) {
      float p0 = exp2f(fmaf(s[t][0], c1, -mm));
      float p1 = exp2f(fmaf(s[t][1], c1, -mm));
      float p2 = exp2f(fmaf(s[t][2], c1, -mm));
      float p3 = exp2f(fmaf(s[t][3], c1, -mm));
      lsum += (p0 + p1) + (p2 + p3);
      pk[t][0] = pack2(p0, p1);
      pk[t][1] = pack2(p2, p3);
    }
    pk[25][0] = 0u; pk[25][1] = 0u;
    lsum += __shfl_xor(lsum, 16, 64);
    lsum += __shfl_xor(lsum, 32, 64);

    // ---- PV: o^T = V^T · P^T, 13 chunks of 32 k ----
    f32x4 oT0 = zz, oT1 = zz;
#pragma unroll
    for (int c = 0; c < 13; c++) {
      unsigned lo0 = tsel ? pk[2 * c + 1][0] : pk[2 * c][0];
      unsigned lo1 = tsel ? pk[2 * c + 1][1] : pk[2 * c][1];
      unsigned w0 = (unsigned)__shfl((int)lo0, Lsrc, 64);
      unsigned w1 = (unsigned)__shfl((int)lo1, Lsrc, 64);
      unsigned w2 = (unsigned)__shfl((int)lo0, Lsrc + 16, 64);
      unsigned w3 = (unsigned)__shfl((int)lo1, Lsrc + 16, 64);
      uint4 pw = {w0, w1, w2, w3};
      short8v pf = *reinterpret_cast<const short8v*>(&pw);
      short8v vf0 = *reinterpret_cast<const short8v*>(
          &Vt[ql * 424 + c * 32 + lg * 8]);
      short8v vf1 = *reinterpret_cast<const short8v*>(
          &Vt[(16 + ql) * 424 + c * 32 + lg * 8]);
      oT0 = MFMA16(vf0, pf, oT0);
      oT1 = MFMA16(vf1, pf, oT1);
    }

    // ---- writeback: lane holds o[q=ql][d=4*lg+r (+16)] ----
    int qo = mt * 16 + ql;
    if (qo < 392) {
      float inv = 1.0f / lsum;
      size_t ob = ((size_t)bimg * Ll + tok2l(qo)) * 256 + cb + 4 * lg;
      bf16 o4[4];
#pragma unroll
      for (int r = 0; r < 4; r++) o4[r] = __float2bfloat16(oT0[r] * inv);
      *reinterpret_cast<uint2*>(att + ob) = *reinterpret_cast<const uint2*>(o4);
#pragma unroll
      for (int r = 0; r < 4; r++) o4[r] = __float2bfloat16(oT1[r] * inv);
      *reinterpret_cast<uint2*>(att + ob + 16) = *reinterpret_cast<const uint2*>(o4);
    }
  }
}

// ---------------- LePE depthwise 3x3 (window-local SAME), adds into att ----------------
__global__ __launch_bounds__(256) void lepe_kernel(const bf16* __restrict__ qkv,
    const float* __restrict__ w0, const float* __restrict__ b0,
    const float* __restrict__ w1, const float* __restrict__ b1,
    bf16* __restrict__ att) {
  int idx = blockIdx.x * 256 + threadIdx.x;  // B*L*256 total
  int ch = idx & 255;
  int pos = idx >> 8;  // b*L + l
  int l = pos % Ll;
  int h = l / 56, w = l - (l / 56) * 56;
  int branch = ch >> 7, c2 = ch & 127;
  const float* wp = (branch ? w1 : w0) + c2 * 9;
  float bias = (branch ? b1 : b0)[c2];
  const bf16* vp = qkv + (size_t)pos * 768 + 512 + branch * 128 + c2;
  int lh = branch ? (h % 7) : h;
  int hmax = branch ? 7 : 56;
  int lw = branch ? w : (w % 7);
  int wmax = branch ? 56 : 7;
  float s = bias;
#pragma unroll
  for (int dy = -1; dy <= 1; dy++) {
#pragma unroll
    for (int dx = -1; dx <= 1; dx++) {
      bool ok = (unsigned)(lh + dy) < (unsigned)hmax && (unsigned)(lw + dx) < (unsigned)wmax;
      if (ok)
        s += wp[(dy + 1) * 3 + (dx + 1)] *
             __bfloat162float(vp[(dy * 56 + dx) * 768]);
    }
  }
  size_t o = (size_t)pos * 256 + ch;
  att[o] = __float2bfloat16(__bfloat162float(att[o]) + s);
}

// ---------------- host ----------------
extern "C" void kernel_launch(void* const* d_in, const int* in_sizes, int n_in,
                              void* d_out, int out_size, void* d_ws, size_t ws_size,
                              hipStream_t stream) {
  const float* x_in    = (const float*)d_in[0];
  const float* ln1_g   = (const float*)d_in[1];
  const float* ln1_b   = (const float*)d_in[2];
  const float* qkv_w   = (const float*)d_in[3];
  const float* qkv_b   = (const float*)d_in[4];
  const float* lepe_w0 = (const float*)d_in[5];
  const float* lepe_b0 = (const float*)d_in[6];
  const float* lepe_w1 = (const float*)d_in[7];
  const float* lepe_b1 = (const float*)d_in[8];
  const float* proj_w  = (const float*)d_in[9];
  const float* proj_b  = (const float*)d_in[10];
  const float* ln2_g   = (const float*)d_in[11];
  const float* ln2_b   = (const float*)d_in[12];
  const float* fc1_w   = (const float*)d_in[13];
  const float* fc1_b   = (const float*)d_in[14];
  const float* fc2_w   = (const float*)d_in[15];
  const float* fc2_b   = (const float*)d_in[16];
  float* xf = (float*)d_out;

  char* ws = (char*)d_ws;
  bf16* wT   = (bf16*)ws;                                   // 3,145,728 B
  bf16* bufA = (bf16*)(ws + 3145728);                       // qkv / mlp-h: 51,380,224 B
  bf16* imgB = (bf16*)(ws + 3145728 + 51380224);            // 12,845,056 B
  bf16* attB = (bf16*)(ws + 3145728 + 51380224 + 12845056); // 12,845,056 B

  // x <- input (residual stream lives in d_out, f32)
  hipMemcpyAsync(d_out, (const void*)x_in, (size_t)Mrows * 256 * 4,
                 hipMemcpyDeviceToDevice, stream);

  // transpose+cast all weights to bf16 [N][K]
  for (int l = 0; l < 2; l++) {
    bf16* qkvT = wT + (size_t)l * 786432;
    bf16* projT = qkvT + 196608;
    bf16* fc1T  = qkvT + 262144;
    bf16* fc2T  = qkvT + 524288;
    wtrans_kernel<<<256, 256, 0, stream>>>(qkv_w + l * 196608, qkvT, 256, 768);
    wtrans_kernel<<<128, 256, 0, stream>>>(proj_w + l * 65536, projT, 256, 256);
    wtrans_kernel<<<256, 256, 0, stream>>>(fc1_w + l * 262144, fc1T, 256, 1024);
    wtrans_kernel<<<256, 256, 0, stream>>>(fc2_w + l * 262144, fc2T, 1024, 256);
  }

  for (int l = 0; l < 2; l++) {
    bf16* qkvT = wT + (size_t)l * 786432;
    bf16* projT = qkvT + 196608;
    bf16* fc1T  = qkvT + 262144;
    bf16* fc2T  = qkvT + 524288;

    ln_kernel<<<Mrows / 4, 256, 0, stream>>>(xf, ln1_g + l * 256, ln1_b + l * 256, imgB);
    gemm_kernel<0><<<dim3(6, 196), 256, 0, stream>>>(imgB, qkvT, qkv_b + l * 768,
                                                     bufA, Mrows, 768, 256);
    attn_kernel<<<512, 256, 0, stream>>>(bufA, attB);
    lepe_kernel<<<Mrows, 256, 0, stream>>>(bufA, lepe_w0 + l * 1152, lepe_b0 + l * 128,
                                           lepe_w1 + l * 1152, lepe_b1 + l * 128, attB);
    gemm_kernel<2><<<dim3(2, 196), 256, 0, stream>>>(attB, projT, proj_b + l * 256,
                                                     xf, Mrows, 256, 256);
    ln_kernel<<<Mrows / 4, 256, 0, stream>>>(xf, ln2_g + l * 256, ln2_b + l * 256, imgB);
    gemm_kernel<1><<<dim3(8, 196), 256, 0, stream>>>(imgB, fc1T, fc1_b + l * 1024,
                                                     bufA, Mrows, 1024, 256);
    gemm_kernel<2><<<dim3(2, 196), 256, 0, stream>>>(bufA, fc2T, fc2_b + l * 256,
                                                     xf, Mrows, 256, 1024);
  }
}